// Round 6
// baseline (513.609 us; speedup 1.0000x reference)
//
#include <hip/hip_runtime.h>

typedef __attribute__((ext_vector_type(8))) __bf16 bf16x8;
typedef __attribute__((ext_vector_type(4))) float f32x4;

#define N_ 1024
#define C_ 64
#define BP_ 48

static __device__ __forceinline__ unsigned short f2bf(float f) {
    __bf16 b = (__bf16)f;
    return __builtin_bit_cast(unsigned short, b);
}
static __device__ __forceinline__ unsigned int pack2(float a, float b) {
    return (unsigned int)f2bf(a) | ((unsigned int)f2bf(b) << 16);
}

// ---------------------------------------------------------------------------
// K1: v1/v2 fold of W_emb, s1/s2 per node, per-wave max(s2) -> M2part, and
// bf16 transpose xT[bp][c][j].  grid (16 j-tiles, 48 bp), block 256 (4 waves).
// ---------------------------------------------------------------------------
__global__ __launch_bounds__(256) void gat_pre(
    const float* __restrict__ x, const float* __restrict__ Wemb,
    const float* __restrict__ a1, const float* __restrict__ a2,
    float* __restrict__ s1g, float* __restrict__ s2g,
    unsigned short* __restrict__ xT, float* __restrict__ M2part)
{
    __shared__ float xs[64][65];
    __shared__ float vs[2][64];
    const int t = threadIdx.x, l = t & 63, w = t >> 6;
    const int j0 = blockIdx.x * 64;
    const int bp = blockIdx.y;

    if (w == 0) {   // v1[c]=sum_h a1[h]*W_emb[h][c]  (x_emb folds away)
        float v1 = 0.f, v2 = 0.f;
        #pragma unroll 8
        for (int h = 0; h < 64; ++h) {
            float we = Wemb[h * 64 + l];
            v1 = fmaf(a1[h], we, v1);
            v2 = fmaf(a2[h], we, v2);
        }
        vs[0][l] = v1; vs[1][l] = v2;
    }
    const float* xb = x + ((size_t)bp * N_ + j0) * C_;
    #pragma unroll
    for (int it = 0; it < 16; ++it)
        xs[it * 4 + w][l] = xb[(it * 4 + w) * C_ + l];
    __syncthreads();

    // partial dot: row j = t>>2, channel quarter t&3; 2-shuffle reduce
    const int jr = t >> 2, c0 = (t & 3) * 16;
    float p1 = 0.f, p2 = 0.f;
    #pragma unroll
    for (int k = 0; k < 16; ++k) {
        float xv = xs[jr][c0 + k];
        p1 = fmaf(xv, vs[0][c0 + k], p1);
        p2 = fmaf(xv, vs[1][c0 + k], p2);
    }
    p1 += __shfl_xor(p1, 1); p1 += __shfl_xor(p1, 2);
    p2 += __shfl_xor(p2, 1); p2 += __shfl_xor(p2, 2);
    if ((l & 3) == 0) {
        s1g[bp * N_ + j0 + jr] = p1;
        s2g[bp * N_ + j0 + jr] = p2;
    }
    float m = p2;
    m = fmaxf(m, __shfl_xor(m, 4));
    m = fmaxf(m, __shfl_xor(m, 8));
    m = fmaxf(m, __shfl_xor(m, 16));
    m = fmaxf(m, __shfl_xor(m, 32));
    if (l == 0) M2part[bp * 64 + blockIdx.x * 4 + w] = m;

    // bf16 transpose out: thread t handles c = t>>2, 16 j's
    const int c = t >> 2, part = t & 3;
    unsigned int ow[8];
    #pragma unroll
    for (int k = 0; k < 16; k += 2) {
        unsigned int lo = f2bf(xs[part * 16 + k][c]);
        unsigned int hi = f2bf(xs[part * 16 + k + 1][c]);
        ow[k >> 1] = lo | (hi << 16);
    }
    uint4* dst = (uint4*)(xT + (size_t)bp * C_ * N_ + (size_t)c * N_ + j0 + part * 16);
    dst[0] = make_uint4(ow[0], ow[1], ow[2], ow[3]);
    dst[1] = make_uint4(ow[4], ow[5], ow[6], ow[7]);
}

// ---------------------------------------------------------------------------
// K2 (fused, software-pipelined): A passthrough + mask + softmax + agg +
// W_lin + sigmoid.  The A stream is double-buffered in registers at
// half-chunk (8-row) granularity: loads for half h+1 issue BEFORE the
// exp/store/LDS/MFMA consumption of half h, so every wave keeps ~8KB of HBM
// loads in flight under the compute tail (R5 failure: VGPR=80 -> serial
// load->drain->compute).  grid (16,48), block 256 = 4 waves x 16 rows.
// ---------------------------------------------------------------------------
__global__ __launch_bounds__(256, 3) void gat_fused(
    const float* __restrict__ Ag, float* __restrict__ outA,
    const unsigned short* __restrict__ xT,
    const float* __restrict__ s1g, const float* __restrict__ s2g,
    const float* __restrict__ M2part,
    const float* __restrict__ Wlin, float* __restrict__ out)
{
    // per-wave P tile: 16 rows x 256 j bf16, row stride 264 ushort (8 pad)
    __shared__ unsigned short Plds[4][16][264];
    const int l = threadIdx.x & 63, w = threadIdx.x >> 6;
    const int i15 = l & 15, q = l >> 4;
    const int bp = blockIdx.y;
    const int ibase = blockIdx.x * 64 + w * 16;

    // reduce per-wave maxima -> M2 (once; 6 shuffles)
    float m2v = M2part[bp * 64 + l];
    #pragma unroll
    for (int off = 32; off >= 1; off >>= 1)
        m2v = fmaxf(m2v, __shfl_xor(m2v, off));
    const float M2 = m2v;

    const float s1_l = s1g[bp * N_ + ibase + i15];   // lane rr holds s1 of row rr
    float s1r[16];
    #pragma unroll
    for (int rr = 0; rr < 16; ++rr) s1r[rr] = __shfl(s1_l, rr);

    const float* Arow = Ag + (size_t)bp * N_ * N_ + (size_t)ibase * N_;
    float* oArow = outA + (size_t)bp * N_ * N_ + (size_t)ibase * N_;
    const unsigned short* xTb = xT + (size_t)bp * C_ * N_;

    // all 4 chunks of s2 up front (16 VGPRs) — no dependent load at chunk top
    f32x4 s2pc[4];
    #pragma unroll
    for (int c = 0; c < 4; ++c)
        s2pc[c] = *(const f32x4*)&s2g[bp * N_ + c * 256 + 4 * l];

    f32x4 acc[4] = {};                 // rows q*4+r, c = nt*16+i15
    float lsum[16];
    #pragma unroll
    for (int rr = 0; rr < 16; ++rr) lsum[rr] = 0.f;

    // prime the pipeline: half 0 = chunk 0, rows 0..7
    f32x4 Abuf[2][8];
    #pragma unroll
    for (int r = 0; r < 8; ++r)
        Abuf[0][r] = __builtin_nontemporal_load(
            (const f32x4*)&Arow[(size_t)r * N_ + 4 * l]);

    #pragma unroll
    for (int h = 0; h < 8; ++h) {                  // 8 half-chunks
        const int jc = h >> 1, rbase = (h & 1) * 8, j0c = jc * 256;
        if (h < 7) {                               // issue loads for half h+1
            const int jn = ((h + 1) >> 1) * 256, rbn = ((h + 1) & 1) * 8;
            #pragma unroll
            for (int r = 0; r < 8; ++r)
                Abuf[(h + 1) & 1][r] = __builtin_nontemporal_load(
                    (const f32x4*)&Arow[(size_t)(rbn + r) * N_ + jn + 4 * l]);
        }
        #pragma unroll
        for (int r = 0; r < 8; ++r) {              // consume half h
            const int rr = rbase + r;
            f32x4 Av = Abuf[h & 1][r];
            __builtin_nontemporal_store(Av,
                (f32x4*)&oArow[(size_t)rr * N_ + j0c + 4 * l]);   // A passthrough
            float zr = s1r[rr] + M2;
            float mrr = fmaxf(zr, 0.01f * zr);     // fixed softmax shift (recomputed)
            float e[4];
            #pragma unroll
            for (int k = 0; k < 4; ++k) {
                float zz = s1r[rr] + s2pc[jc][k];
                zz = fmaxf(zz, 0.01f * zz);        // leaky_relu
                e[k] = (Av[k] != 0.f) ? __expf(zz - mrr) : 0.f;
            }
            lsum[rr] += (e[0] + e[1]) + (e[2] + e[3]);
            *(uint2*)&Plds[w][rr][4 * l] =
                make_uint2(pack2(e[0], e[1]), pack2(e[2], e[3]));
        }
        if (h & 1) {   // chunk complete -> acc += P_chunk @ X_chunk (M16 N64 K256)
            #pragma unroll
            for (int s = 0; s < 8; ++s) {
                bf16x8 af = *(const bf16x8*)&Plds[w][i15][s * 32 + q * 8];
                #pragma unroll
                for (int nt = 0; nt < 4; ++nt) {
                    bf16x8 bfr = *(const bf16x8*)&xTb[(size_t)(nt * 16 + i15) * N_ +
                                                      j0c + s * 32 + q * 8];
                    acc[nt] = __builtin_amdgcn_mfma_f32_16x16x32_bf16(af, bfr, acc[nt], 0, 0, 0);
                }
            }
        }
    }

    // one deferred l-sum reduction per row (16 independent chains)
    #pragma unroll
    for (int rr = 0; rr < 16; ++rr)
        #pragma unroll
        for (int off = 32; off >= 1; off >>= 1)
            lsum[rr] += __shfl_xor(lsum[rr], off);

    // ---- epilogue: agg = acc/l, LDS round-trip to A-layout, @W_lin^T, sigmoid
    unsigned short* aggl = &Plds[w][0][0];   // reuse own P slice, stride 72
    #pragma unroll
    for (int nt = 0; nt < 4; ++nt)
        #pragma unroll
        for (int r = 0; r < 4; ++r) {
            int row = q * 4 + r;
            aggl[row * 72 + nt * 16 + i15] = f2bf(acc[nt][r] / lsum[row]);
        }
    f32x4 d2[4] = {};
    #pragma unroll
    for (int s = 0; s < 2; ++s) {
        bf16x8 af = *(const bf16x8*)&aggl[i15 * 72 + s * 32 + q * 8];
        #pragma unroll
        for (int nt = 0; nt < 4; ++nt) {
            const float* wp = Wlin + (size_t)(nt * 16 + i15) * C_ + s * 32 + q * 8;
            f32x4 w0 = *(const f32x4*)wp;
            f32x4 w1 = *(const f32x4*)(wp + 4);
            bf16x8 bfr;
            #pragma unroll
            for (int jj = 0; jj < 4; ++jj) { bfr[jj] = (__bf16)w0[jj]; bfr[4 + jj] = (__bf16)w1[jj]; }
            d2[nt] = __builtin_amdgcn_mfma_f32_16x16x32_bf16(af, bfr, d2[nt], 0, 0, 0);
        }
    }
    float* orow = out + ((size_t)bp * N_ + ibase) * C_;
    #pragma unroll
    for (int nt = 0; nt < 4; ++nt)
        #pragma unroll
        for (int r = 0; r < 4; ++r)
            orow[(size_t)(q * 4 + r) * C_ + nt * 16 + i15] =
                1.f / (1.f + __expf(-d2[nt][r]));
}

extern "C" void kernel_launch(void* const* d_in, const int* in_sizes, int n_in,
                              void* d_out, int out_size, void* d_ws, size_t ws_size,
                              hipStream_t stream) {
    const float* x    = (const float*)d_in[0];
    const float* Ag   = (const float*)d_in[1];
    const float* Wemb = (const float*)d_in[2];
    const float* a1   = (const float*)d_in[3];
    const float* a2   = (const float*)d_in[4];
    const float* Wlin = (const float*)d_in[5];
    float* out  = (float*)d_out;
    float* outA = out + (size_t)BP_ * N_ * C_;   // tuple output #2: A passthrough

    // ws layout (~6.7 MB total)
    float* s1g = (float*)d_ws;                               // 48K f32
    float* s2g = s1g + BP_ * N_;                             // 48K f32
    float* M2part = s2g + BP_ * N_;                          // 48*64 f32
    unsigned short* xT = (unsigned short*)(M2part + BP_ * 64);   // 6.3MB bf16

    gat_pre<<<dim3(16, BP_), dim3(256), 0, stream>>>(x, Wemb, a1, a2,
                                                     s1g, s2g, xT, M2part);
    gat_fused<<<dim3(16, BP_), dim3(256), 0, stream>>>(Ag, outA, xT, s1g, s2g,
                                                       M2part, Wlin, out);
}

// Round 7
// 484.618 us; speedup vs baseline: 1.0598x; 1.0598x over previous
//
#include <hip/hip_runtime.h>

typedef __attribute__((ext_vector_type(8))) __bf16 bf16x8;
typedef __attribute__((ext_vector_type(4))) float f32x4;

#define N_ 1024
#define C_ 64
#define BP_ 48

static __device__ __forceinline__ unsigned short f2bf(float f) {
    __bf16 b = (__bf16)f;
    return __builtin_bit_cast(unsigned short, b);
}
static __device__ __forceinline__ unsigned int pack2(float a, float b) {
    return (unsigned int)f2bf(a) | ((unsigned int)f2bf(b) << 16);
}

// ---------------------------------------------------------------------------
// K1: v1/v2 fold of W_emb, s1/s2 per node, per-wave max(s2) -> M2part, and
// bf16 transpose xT[bp][c][j].  grid (16 j-tiles, 48 bp), block 256 (4 waves).
// ---------------------------------------------------------------------------
__global__ __launch_bounds__(256) void gat_pre(
    const float* __restrict__ x, const float* __restrict__ Wemb,
    const float* __restrict__ a1, const float* __restrict__ a2,
    float* __restrict__ s1g, float* __restrict__ s2g,
    unsigned short* __restrict__ xT, float* __restrict__ M2part)
{
    __shared__ float xs[64][65];
    __shared__ float vs[2][64];
    const int t = threadIdx.x, l = t & 63, w = t >> 6;
    const int j0 = blockIdx.x * 64;
    const int bp = blockIdx.y;

    if (w == 0) {   // v1[c]=sum_h a1[h]*W_emb[h][c]  (x_emb folds away)
        float v1 = 0.f, v2 = 0.f;
        #pragma unroll 8
        for (int h = 0; h < 64; ++h) {
            float we = Wemb[h * 64 + l];
            v1 = fmaf(a1[h], we, v1);
            v2 = fmaf(a2[h], we, v2);
        }
        vs[0][l] = v1; vs[1][l] = v2;
    }
    const float* xb = x + ((size_t)bp * N_ + j0) * C_;
    #pragma unroll
    for (int it = 0; it < 16; ++it)
        xs[it * 4 + w][l] = xb[(it * 4 + w) * C_ + l];
    __syncthreads();

    // partial dot: row j = t>>2, channel quarter t&3; 2-shuffle reduce
    const int jr = t >> 2, c0 = (t & 3) * 16;
    float p1 = 0.f, p2 = 0.f;
    #pragma unroll
    for (int k = 0; k < 16; ++k) {
        float xv = xs[jr][c0 + k];
        p1 = fmaf(xv, vs[0][c0 + k], p1);
        p2 = fmaf(xv, vs[1][c0 + k], p2);
    }
    p1 += __shfl_xor(p1, 1); p1 += __shfl_xor(p1, 2);
    p2 += __shfl_xor(p2, 1); p2 += __shfl_xor(p2, 2);
    if ((l & 3) == 0) {
        s1g[bp * N_ + j0 + jr] = p1;
        s2g[bp * N_ + j0 + jr] = p2;
    }
    float m = p2;
    m = fmaxf(m, __shfl_xor(m, 4));
    m = fmaxf(m, __shfl_xor(m, 8));
    m = fmaxf(m, __shfl_xor(m, 16));
    m = fmaxf(m, __shfl_xor(m, 32));
    if (l == 0) M2part[bp * 64 + blockIdx.x * 4 + w] = m;

    // bf16 transpose out: thread t handles c = t>>2, 16 j's
    const int c = t >> 2, part = t & 3;
    unsigned int ow[8];
    #pragma unroll
    for (int k = 0; k < 16; k += 2) {
        unsigned int lo = f2bf(xs[part * 16 + k][c]);
        unsigned int hi = f2bf(xs[part * 16 + k + 1][c]);
        ow[k >> 1] = lo | (hi << 16);
    }
    uint4* dst = (uint4*)(xT + (size_t)bp * C_ * N_ + (size_t)c * N_ + j0 + part * 16);
    dst[0] = make_uint4(ow[0], ow[1], ow[2], ow[3]);
    dst[1] = make_uint4(ow[4], ow[5], ow[6], ow[7]);
}

// ---------------------------------------------------------------------------
// Pipeline step for half-chunk H (8 rows of a 256-j chunk): issue the 8
// prefetch loads for half H+1 into `nxt`, then consume `cur` (A passthrough
// store, masked exp, P->LDS).  ALL array indices are compile-time constants
// (named buffers alternate by POSITION in the caller) so SROA must put both
// buffers in registers — this is the fix for R5 (load sinking, VGPR=80) and
// R6 (alloca->scratch, +400MB HBM).
// ---------------------------------------------------------------------------
template<int H>
static __device__ __forceinline__ void half_step(
    f32x4 (&cur)[8], f32x4 (&nxt)[8],
    const float* __restrict__ Arow, float* __restrict__ oArow,
    const float (&s1r)[16], float M2, const f32x4 (&s2pc)[4],
    float (&lsum)[16], unsigned short* Pw, int l)
{
    constexpr int jc = H >> 1;
    constexpr int rbase = (H & 1) * 8;
    constexpr int j0c = jc * 256;
    if constexpr (H < 7) {
        constexpr int jn  = ((H + 1) >> 1) * 256;
        constexpr int rbn = ((H + 1) & 1) * 8;
        #pragma unroll
        for (int r = 0; r < 8; ++r)
            nxt[r] = __builtin_nontemporal_load(
                (const f32x4*)&Arow[(size_t)(rbn + r) * N_ + jn + 4 * l]);
    }
    #pragma unroll
    for (int r = 0; r < 8; ++r) {
        constexpr int dummy = 0; (void)dummy;
        const int rr = rbase + r;
        f32x4 Av = cur[r];
        __builtin_nontemporal_store(Av,
            (f32x4*)&oArow[(size_t)rr * N_ + j0c + 4 * l]);   // A passthrough
        float zr = s1r[rr] + M2;
        float mrr = fmaxf(zr, 0.01f * zr);       // fixed softmax shift
        float e[4];
        #pragma unroll
        for (int k = 0; k < 4; ++k) {
            float zz = s1r[rr] + s2pc[jc][k];
            zz = fmaxf(zz, 0.01f * zz);          // leaky_relu
            e[k] = (Av[k] != 0.f) ? __expf(zz - mrr) : 0.f;
        }
        lsum[rr] += (e[0] + e[1]) + (e[2] + e[3]);
        *(uint2*)&Pw[rr * 264 + 4 * l] =
            make_uint2(pack2(e[0], e[1]), pack2(e[2], e[3]));
    }
}

static __device__ __forceinline__ void mfma_chunk(
    int j0c, const unsigned short* Pw, const unsigned short* __restrict__ xTb,
    f32x4 (&acc)[4], int i15, int q)
{
    #pragma unroll
    for (int s = 0; s < 8; ++s) {
        bf16x8 af = *(const bf16x8*)&Pw[i15 * 264 + s * 32 + q * 8];
        #pragma unroll
        for (int nt = 0; nt < 4; ++nt) {
            bf16x8 bfr = *(const bf16x8*)&xTb[(size_t)(nt * 16 + i15) * N_ +
                                              j0c + s * 32 + q * 8];
            acc[nt] = __builtin_amdgcn_mfma_f32_16x16x32_bf16(af, bfr, acc[nt], 0, 0, 0);
        }
    }
}

// ---------------------------------------------------------------------------
// K2 (fused, hand-pipelined): A passthrough + mask + softmax + agg + W_lin +
// sigmoid.  8 half-chunks, register double-buffer via named arrays A0/A1.
// grid (16,48) = 3 blocks/CU, block 256 = 4 independent waves x 16 rows.
// ---------------------------------------------------------------------------
__global__ __launch_bounds__(256, 3) void gat_fused(
    const float* __restrict__ Ag, float* __restrict__ outA,
    const unsigned short* __restrict__ xT,
    const float* __restrict__ s1g, const float* __restrict__ s2g,
    const float* __restrict__ M2part,
    const float* __restrict__ Wlin, float* __restrict__ out)
{
    // per-wave P tile: 16 rows x 256 j bf16, row stride 264 ushort (8 pad)
    __shared__ unsigned short Plds[4][16][264];
    const int l = threadIdx.x & 63, w = threadIdx.x >> 6;
    const int i15 = l & 15, q = l >> 4;
    const int bp = blockIdx.y;
    const int ibase = blockIdx.x * 64 + w * 16;

    // reduce per-wave maxima -> M2 (once; 6 shuffles)
    float m2v = M2part[bp * 64 + l];
    #pragma unroll
    for (int off = 32; off >= 1; off >>= 1)
        m2v = fmaxf(m2v, __shfl_xor(m2v, off));
    const float M2 = m2v;

    const float s1_l = s1g[bp * N_ + ibase + i15];   // lane rr holds s1 of row rr
    float s1r[16];
    #pragma unroll
    for (int rr = 0; rr < 16; ++rr) s1r[rr] = __shfl(s1_l, rr);

    const float* Arow = Ag + (size_t)bp * N_ * N_ + (size_t)ibase * N_;
    float* oArow = outA + (size_t)bp * N_ * N_ + (size_t)ibase * N_;
    const unsigned short* xTb = xT + (size_t)bp * C_ * N_;

    // all 4 chunks of s2 up front — no dependent load at chunk top
    f32x4 s2pc[4];
    #pragma unroll
    for (int c = 0; c < 4; ++c)
        s2pc[c] = *(const f32x4*)&s2g[bp * N_ + c * 256 + 4 * l];

    f32x4 acc[4] = {};                 // rows q*4+r, c = nt*16+i15
    float lsum[16];
    #pragma unroll
    for (int rr = 0; rr < 16; ++rr) lsum[rr] = 0.f;

    unsigned short* Pw = &Plds[w][0][0];

    // prime: half 0 (chunk 0, rows 0..7)
    f32x4 A0[8], A1[8];
    #pragma unroll
    for (int r = 0; r < 8; ++r)
        A0[r] = __builtin_nontemporal_load(
            (const f32x4*)&Arow[(size_t)r * N_ + 4 * l]);

    half_step<0>(A0, A1, Arow, oArow, s1r, M2, s2pc, lsum, Pw, l);
    half_step<1>(A1, A0, Arow, oArow, s1r, M2, s2pc, lsum, Pw, l);
    mfma_chunk(0, Pw, xTb, acc, i15, q);
    half_step<2>(A0, A1, Arow, oArow, s1r, M2, s2pc, lsum, Pw, l);
    half_step<3>(A1, A0, Arow, oArow, s1r, M2, s2pc, lsum, Pw, l);
    mfma_chunk(256, Pw, xTb, acc, i15, q);
    half_step<4>(A0, A1, Arow, oArow, s1r, M2, s2pc, lsum, Pw, l);
    half_step<5>(A1, A0, Arow, oArow, s1r, M2, s2pc, lsum, Pw, l);
    mfma_chunk(512, Pw, xTb, acc, i15, q);
    half_step<6>(A0, A1, Arow, oArow, s1r, M2, s2pc, lsum, Pw, l);
    half_step<7>(A1, A0, Arow, oArow, s1r, M2, s2pc, lsum, Pw, l);
    mfma_chunk(768, Pw, xTb, acc, i15, q);

    // one deferred l-sum reduction per row (16 independent chains)
    #pragma unroll
    for (int rr = 0; rr < 16; ++rr)
        #pragma unroll
        for (int off = 32; off >= 1; off >>= 1)
            lsum[rr] += __shfl_xor(lsum[rr], off);

    // ---- epilogue: agg = acc/l, LDS round-trip to A-layout, @W_lin^T, sigmoid
    unsigned short* aggl = Pw;               // reuse own P slice, stride 72
    #pragma unroll
    for (int nt = 0; nt < 4; ++nt)
        #pragma unroll
        for (int r = 0; r < 4; ++r) {
            int row = q * 4 + r;
            aggl[row * 72 + nt * 16 + i15] = f2bf(acc[nt][r] / lsum[row]);
        }
    f32x4 d2[4] = {};
    #pragma unroll
    for (int s = 0; s < 2; ++s) {
        bf16x8 af = *(const bf16x8*)&aggl[i15 * 72 + s * 32 + q * 8];
        #pragma unroll
        for (int nt = 0; nt < 4; ++nt) {
            const float* wp = Wlin + (size_t)(nt * 16 + i15) * C_ + s * 32 + q * 8;
            f32x4 w0 = *(const f32x4*)wp;
            f32x4 w1 = *(const f32x4*)(wp + 4);
            bf16x8 bfr;
            #pragma unroll
            for (int jj = 0; jj < 4; ++jj) { bfr[jj] = (__bf16)w0[jj]; bfr[4 + jj] = (__bf16)w1[jj]; }
            d2[nt] = __builtin_amdgcn_mfma_f32_16x16x32_bf16(af, bfr, d2[nt], 0, 0, 0);
        }
    }
    float* orow = out + ((size_t)bp * N_ + ibase) * C_;
    #pragma unroll
    for (int nt = 0; nt < 4; ++nt)
        #pragma unroll
        for (int r = 0; r < 4; ++r)
            orow[(size_t)(q * 4 + r) * C_ + nt * 16 + i15] =
                1.f / (1.f + __expf(-d2[nt][r]));
}

extern "C" void kernel_launch(void* const* d_in, const int* in_sizes, int n_in,
                              void* d_out, int out_size, void* d_ws, size_t ws_size,
                              hipStream_t stream) {
    const float* x    = (const float*)d_in[0];
    const float* Ag   = (const float*)d_in[1];
    const float* Wemb = (const float*)d_in[2];
    const float* a1   = (const float*)d_in[3];
    const float* a2   = (const float*)d_in[4];
    const float* Wlin = (const float*)d_in[5];
    float* out  = (float*)d_out;
    float* outA = out + (size_t)BP_ * N_ * C_;   // tuple output #2: A passthrough

    // ws layout (~6.7 MB total)
    float* s1g = (float*)d_ws;                               // 48K f32
    float* s2g = s1g + BP_ * N_;                             // 48K f32
    float* M2part = s2g + BP_ * N_;                          // 48*64 f32
    unsigned short* xT = (unsigned short*)(M2part + BP_ * 64);   // 6.3MB bf16

    gat_pre<<<dim3(16, BP_), dim3(256), 0, stream>>>(x, Wemb, a1, a2,
                                                     s1g, s2g, xT, M2part);
    gat_fused<<<dim3(16, BP_), dim3(256), 0, stream>>>(Ag, outA, xT, s1g, s2g,
                                                       M2part, Wlin, out);
}

// Round 8
// 394.214 us; speedup vs baseline: 1.3029x; 1.2293x over previous
//
#include <hip/hip_runtime.h>

typedef __attribute__((ext_vector_type(8))) __bf16 bf16x8;
typedef __attribute__((ext_vector_type(4))) float f32x4;

#define N_ 1024
#define C_ 64
#define BP_ 48

static __device__ __forceinline__ unsigned short f2bf(float f) {
    __bf16 b = (__bf16)f;
    return __builtin_bit_cast(unsigned short, b);
}
static __device__ __forceinline__ unsigned int pack2(float a, float b) {
    return (unsigned int)f2bf(a) | ((unsigned int)f2bf(b) << 16);
}
// global->LDS DMA, 16B/lane: LDS gets base + 16*lane (wave-uniform base!)
static __device__ __forceinline__ void load_lds16(const float* g, float* s) {
    __builtin_amdgcn_global_load_lds(
        (__attribute__((address_space(1))) void*)(void*)g,
        (__attribute__((address_space(3))) void*)s, 16, 0, 0);
}

// ---------------------------------------------------------------------------
// K1: v1/v2 fold of W_emb, s1/s2 per node, per-wave max(s2) -> M2part, and
// bf16 transpose xT[bp][c][j].  grid (16 j-tiles, 48 bp), block 256 (4 waves).
// ---------------------------------------------------------------------------
__global__ __launch_bounds__(256) void gat_pre(
    const float* __restrict__ x, const float* __restrict__ Wemb,
    const float* __restrict__ a1, const float* __restrict__ a2,
    float* __restrict__ s1g, float* __restrict__ s2g,
    unsigned short* __restrict__ xT, float* __restrict__ M2part)
{
    __shared__ float xs[64][65];
    __shared__ float vs[2][64];
    const int t = threadIdx.x, l = t & 63, w = t >> 6;
    const int j0 = blockIdx.x * 64;
    const int bp = blockIdx.y;

    if (w == 0) {   // v1[c]=sum_h a1[h]*W_emb[h][c]  (x_emb folds away)
        float v1 = 0.f, v2 = 0.f;
        #pragma unroll 8
        for (int h = 0; h < 64; ++h) {
            float we = Wemb[h * 64 + l];
            v1 = fmaf(a1[h], we, v1);
            v2 = fmaf(a2[h], we, v2);
        }
        vs[0][l] = v1; vs[1][l] = v2;
    }
    const float* xb = x + ((size_t)bp * N_ + j0) * C_;
    #pragma unroll
    for (int it = 0; it < 16; ++it)
        xs[it * 4 + w][l] = xb[(it * 4 + w) * C_ + l];
    __syncthreads();

    const int jr = t >> 2, c0 = (t & 3) * 16;
    float p1 = 0.f, p2 = 0.f;
    #pragma unroll
    for (int k = 0; k < 16; ++k) {
        float xv = xs[jr][c0 + k];
        p1 = fmaf(xv, vs[0][c0 + k], p1);
        p2 = fmaf(xv, vs[1][c0 + k], p2);
    }
    p1 += __shfl_xor(p1, 1); p1 += __shfl_xor(p1, 2);
    p2 += __shfl_xor(p2, 1); p2 += __shfl_xor(p2, 2);
    if ((l & 3) == 0) {
        s1g[bp * N_ + j0 + jr] = p1;
        s2g[bp * N_ + j0 + jr] = p2;
    }
    float m = p2;
    m = fmaxf(m, __shfl_xor(m, 4));
    m = fmaxf(m, __shfl_xor(m, 8));
    m = fmaxf(m, __shfl_xor(m, 16));
    m = fmaxf(m, __shfl_xor(m, 32));
    if (l == 0) M2part[bp * 64 + blockIdx.x * 4 + w] = m;

    const int c = t >> 2, part = t & 3;
    unsigned int ow[8];
    #pragma unroll
    for (int k = 0; k < 16; k += 2) {
        unsigned int lo = f2bf(xs[part * 16 + k][c]);
        unsigned int hi = f2bf(xs[part * 16 + k + 1][c]);
        ow[k >> 1] = lo | (hi << 16);
    }
    uint4* dst = (uint4*)(xT + (size_t)bp * C_ * N_ + (size_t)c * N_ + j0 + part * 16);
    dst[0] = make_uint4(ow[0], ow[1], ow[2], ow[3]);
    dst[1] = make_uint4(ow[4], ow[5], ow[6], ow[7]);
}

// ---------------------------------------------------------------------------
// K2 (fused, DMA-pipelined): A stream staged global->LDS via
// global_load_lds (no VGPR staging -> nothing to spill; fixes R5/R6/R7).
// Per-wave double-buffered 64-j chunks; one s_waitcnt vmcnt(0) per chunk
// BEFORE issuing the next chunk's DMA -> loads in flight across the whole
// consume+MFMA (~1200cyc > 900cyc HBM latency).  No barrier in the loop.
// grid (16,48), block 256 = 4 independent waves x 16 rows; 3 blocks/CU.
// ---------------------------------------------------------------------------
__global__ __launch_bounds__(256) void gat_fused(
    const float* __restrict__ Ag, float* __restrict__ outA,
    const unsigned short* __restrict__ xT,
    const float* __restrict__ s1g, const float* __restrict__ s2g,
    const float* __restrict__ M2part,
    const float* __restrict__ Wlin, float* __restrict__ out)
{
    __shared__ float ldsA[4][2][1024];          // 32 KB  [wave][buf][16r x 64j]
    __shared__ unsigned short Plds[4][16][72];  // 9 KB   per-wave P tile (pad 8)
    __shared__ float s2lds[1024];               // 4 KB   s2 row, block-shared
    __shared__ float lsLDS[4][16];              // 256 B  per-wave row sums

    const int t = threadIdx.x, l = t & 63, w = t >> 6;
    const int i15 = l & 15, q = l >> 4;
    const int lm = l & 15, g16 = l >> 4;        // aliases for clarity
    const int bp = blockIdx.y;
    const int ibase = blockIdx.x * 64 + w * 16;

    // stage s2 (1024 f32) to LDS, block-wide
    *(f32x4*)&s2lds[4 * t] = *(const f32x4*)&s2g[bp * N_ + 4 * t];

    float m2v = M2part[bp * 64 + l];
    #pragma unroll
    for (int off = 32; off >= 1; off >>= 1)
        m2v = fmaxf(m2v, __shfl_xor(m2v, off));
    const float M2 = m2v;
    const float s1_l = s1g[bp * N_ + ibase + i15];   // lane rr holds s1 of row rr

    __syncthreads();   // s2lds ready (only barrier in the kernel)

    const float* Arow = Ag + (size_t)bp * N_ * N_ + (size_t)ibase * N_;
    float* oArow = outA + (size_t)bp * N_ * N_ + (size_t)ibase * N_;
    const unsigned short* xTb = xT + (size_t)bp * C_ * N_;

    f32x4 acc[4] = {};                  // rows q*4+r, c = nt*16+i15
    float ls4[4] = {0.f, 0.f, 0.f, 0.f};  // lane partial lsum of row 4*sr+g16

    // prime: chunk 0 -> buf 0   (DMA instr r4 covers rows 4r4..4r4+3)
    #pragma unroll
    for (int r4 = 0; r4 < 4; ++r4)
        load_lds16(&Arow[(size_t)(4 * r4 + g16) * N_ + 4 * lm],
                   &ldsA[w][0][r4 * 256]);

    for (int k = 0; k < 16; ++k) {
        // wait chunk-k DMA (issued one iteration ago) + old stores
        asm volatile("s_waitcnt vmcnt(0)" ::: "memory");
        const int cb = k & 1;
        const int j0c = k * 64;
        if (k < 15) {                   // issue chunk k+1 DMA into other buf
            #pragma unroll
            for (int r4 = 0; r4 < 4; ++r4)
                load_lds16(&Arow[(size_t)(4 * r4 + g16) * N_ + j0c + 64 + 4 * lm],
                           &ldsA[w][cb ^ 1][r4 * 256]);
        }
        const f32x4 s2v = *(const f32x4*)&s2lds[j0c + 4 * lm];
        #pragma unroll
        for (int sr = 0; sr < 4; ++sr) {    // consume: rows 4sr+g16, cols 4lm
            f32x4 Av = *(const f32x4*)&ldsA[w][cb][sr * 256 + 4 * l];
            *(f32x4*)&oArow[(size_t)(4 * sr + g16) * N_ + j0c + 4 * lm] = Av;
            float s1v = __shfl(s1_l, 4 * sr + g16);
            float zr = s1v + M2;
            float mv = fmaxf(zr, 0.01f * zr);       // fixed softmax shift
            float e[4];
            #pragma unroll
            for (int kk = 0; kk < 4; ++kk) {
                float zz = s1v + s2v[kk];
                zz = fmaxf(zz, 0.01f * zz);         // leaky_relu
                e[kk] = (Av[kk] != 0.f) ? __expf(zz - mv) : 0.f;
            }
            ls4[sr] += (e[0] + e[1]) + (e[2] + e[3]);
            *(uint2*)&Plds[w][4 * sr + g16][4 * lm] =
                make_uint2(pack2(e[0], e[1]), pack2(e[2], e[3]));
        }
        // acc += P_chunk @ X_chunk   (M16 x N64 x K64 per wave)
        #pragma unroll
        for (int s = 0; s < 2; ++s) {
            bf16x8 af = *(const bf16x8*)&Plds[w][i15][s * 32 + q * 8];
            #pragma unroll
            for (int nt = 0; nt < 4; ++nt) {
                bf16x8 bfr = *(const bf16x8*)&xTb[(size_t)(nt * 16 + i15) * N_ +
                                                  j0c + s * 32 + q * 8];
                acc[nt] = __builtin_amdgcn_mfma_f32_16x16x32_bf16(af, bfr, acc[nt], 0, 0, 0);
            }
        }
    }

    // lsum: reduce within 16-lane group (4 shuffles/row-set), exchange via LDS
    #pragma unroll
    for (int sr = 0; sr < 4; ++sr) {
        ls4[sr] += __shfl_xor(ls4[sr], 1);
        ls4[sr] += __shfl_xor(ls4[sr], 2);
        ls4[sr] += __shfl_xor(ls4[sr], 4);
        ls4[sr] += __shfl_xor(ls4[sr], 8);
    }
    if (lm == 0) {
        #pragma unroll
        for (int sr = 0; sr < 4; ++sr)
            lsLDS[w][4 * sr + g16] = ls4[sr];
    }
    const f32x4 lsq = *(const f32x4*)&lsLDS[w][4 * q];   // rows 4q..4q+3

    // ---- epilogue: agg = acc/l, LDS round-trip to A-layout, @W_lin^T, sigmoid
    unsigned short* aggl = &Plds[w][0][0];   // reuse P slice, stride 72
    #pragma unroll
    for (int nt = 0; nt < 4; ++nt)
        #pragma unroll
        for (int r = 0; r < 4; ++r)
            aggl[(q * 4 + r) * 72 + nt * 16 + i15] = f2bf(acc[nt][r] / lsq[r]);

    f32x4 d2[4] = {};
    #pragma unroll
    for (int s = 0; s < 2; ++s) {
        bf16x8 af = *(const bf16x8*)&aggl[i15 * 72 + s * 32 + q * 8];
        #pragma unroll
        for (int nt = 0; nt < 4; ++nt) {
            const float* wp = Wlin + (size_t)(nt * 16 + i15) * C_ + s * 32 + q * 8;
            f32x4 w0 = *(const f32x4*)wp;
            f32x4 w1 = *(const f32x4*)(wp + 4);
            bf16x8 bfr;
            #pragma unroll
            for (int jj = 0; jj < 4; ++jj) { bfr[jj] = (__bf16)w0[jj]; bfr[4 + jj] = (__bf16)w1[jj]; }
            d2[nt] = __builtin_amdgcn_mfma_f32_16x16x32_bf16(af, bfr, d2[nt], 0, 0, 0);
        }
    }
    float* orow = out + ((size_t)bp * N_ + ibase) * C_;
    #pragma unroll
    for (int nt = 0; nt < 4; ++nt)
        #pragma unroll
        for (int r = 0; r < 4; ++r)
            orow[(size_t)(q * 4 + r) * C_ + nt * 16 + i15] =
                1.f / (1.f + __expf(-d2[nt][r]));
}

extern "C" void kernel_launch(void* const* d_in, const int* in_sizes, int n_in,
                              void* d_out, int out_size, void* d_ws, size_t ws_size,
                              hipStream_t stream) {
    const float* x    = (const float*)d_in[0];
    const float* Ag   = (const float*)d_in[1];
    const float* Wemb = (const float*)d_in[2];
    const float* a1   = (const float*)d_in[3];
    const float* a2   = (const float*)d_in[4];
    const float* Wlin = (const float*)d_in[5];
    float* out  = (float*)d_out;
    float* outA = out + (size_t)BP_ * N_ * C_;   // tuple output #2: A passthrough

    // ws layout (~6.7 MB total)
    float* s1g = (float*)d_ws;                               // 48K f32
    float* s2g = s1g + BP_ * N_;                             // 48K f32
    float* M2part = s2g + BP_ * N_;                          // 48*64 f32
    unsigned short* xT = (unsigned short*)(M2part + BP_ * 64);   // 6.3MB bf16

    gat_pre<<<dim3(16, BP_), dim3(256), 0, stream>>>(x, Wemb, a1, a2,
                                                     s1g, s2g, xT, M2part);
    gat_fused<<<dim3(16, BP_), dim3(256), 0, stream>>>(Ag, outA, xT, s1g, s2g,
                                                       M2part, Wlin, out);
}